// Round 5
// baseline (173.214 us; speedup 1.0000x reference)
//
#include <hip/hip_runtime.h>
#include <math.h>

#define BATCH 64
#define KSL   32
#define DIM   256
#define NMASK 16384

// DPP move of a double (both 32-bit halves), compile-time ctrl.
// bound_ctrl=false + old=src: invalid source lanes keep own value (min-safe).
template<int CTRL>
__device__ __forceinline__ double dpp_mov_f64(double x) {
  union { double d; int i[2]; } a, r;
  a.d = x;
  r.i[0] = __builtin_amdgcn_update_dpp(a.i[0], a.i[0], CTRL, 0xF, 0xF, false);
  r.i[1] = __builtin_amdgcn_update_dpp(a.i[1], a.i[1], CTRL, 0xF, 0xF, false);
  return r.d;
}

__device__ __forceinline__ double readlane_f64(double x, int lane) {
  union { double d; unsigned long long u; } a; a.d = x;
  int lo = __builtin_amdgcn_readlane((int)(a.u & 0xFFFFFFFFull), lane);
  int hi = __builtin_amdgcn_readlane((int)(a.u >> 32), lane);
  union { unsigned long long u; double d; } r;
  r.u = ((unsigned long long)(unsigned)hi << 32) | (unsigned)lo;
  return r.d;
}

// Branchless select cc[idx] (idx wave-uniform) via 5-level cndmask tree.
// All indices compile-time after unroll -> stays in registers (rule #20).
__device__ __forceinline__ float sel32(const float (&cc)[KSL], int idx) {
  float l0[16], l1[8], l2[4], l3[2];
  bool b4 = (idx & 16) != 0;
  #pragma unroll
  for (int r = 0; r < 16; ++r) l0[r] = b4 ? cc[r + 16] : cc[r];
  bool b3 = (idx & 8) != 0;
  #pragma unroll
  for (int r = 0; r < 8; ++r) l1[r] = b3 ? l0[r + 8] : l0[r];
  bool b2 = (idx & 4) != 0;
  #pragma unroll
  for (int r = 0; r < 4; ++r) l2[r] = b2 ? l1[r + 4] : l1[r];
  bool b1 = (idx & 2) != 0;
  #pragma unroll
  for (int r = 0; r < 2; ++r) l3[r] = b1 ? l2[r + 2] : l2[r];
  return (idx & 1) ? l3[1] : l3[0];
}

// ---------------------------------------------------------------------------
// Fused kernel (round-3 structure, round-4 solver inner loop):
//   blocks [0,64)        : cost matrix + reference-exact greedy assignment
//                          (fp64 duals, register-resident cost column,
//                          software-pipelined cur0 = c - u0)
//   blocks [64, 64+2048) : mask partial sums (134 MB, full-device streaming)
// __launch_bounds__(256,2): explicit VGPR budget <=256 so cc[]/sel32 stay in
// registers (round 4's 512-thread config was capped at 32 VGPR -> scratch).
// ---------------------------------------------------------------------------
__global__ __launch_bounds__(256, 2) void fused_kernel(
    const float* __restrict__ slots_t, const float* __restrict__ slots_t1,
    const float* __restrict__ masks,
    int* __restrict__ match, float* __restrict__ partial) {
  int tid = threadIdx.x;
  if (blockIdx.x < BATCH) {
    int b = blockIdx.x;
    __shared__ float as[KSL][64];
    __shared__ float bs[KSL][65];   // pad: conflict-free vs as
    __shared__ float cs[KSL][33];   // pad: column read (r*33+col) hits
                                    // bank (r+col)%32 -> conflict-free
    const float* ab = slots_t  + (size_t)b * KSL * DIM;
    const float* bb = slots_t1 + (size_t)b * KSL * DIM;

    // ---- cost[i][j] = ||a_i - b_j|| (fp32) ----
    float acc[4] = {0.f, 0.f, 0.f, 0.f};
    for (int c = 0; c < DIM / 64; ++c) {
      __syncthreads();
      for (int e = tid; e < KSL * 64; e += 256) {
        int kk = e >> 6, dd = e & 63;
        as[kk][dd] = ab[kk * DIM + c * 64 + dd];
        bs[kk][dd] = bb[kk * DIM + c * 64 + dd];
      }
      __syncthreads();
      #pragma unroll
      for (int p4 = 0; p4 < 4; ++p4) {
        int id = p4 * 256 + tid;
        int i = id >> 5, j = id & 31;
        float s = acc[p4];
        #pragma unroll
        for (int dd = 0; dd < 64; ++dd) {
          float df = as[i][dd] - bs[j][dd];
          s = fmaf(df, df, s);
        }
        acc[p4] = s;
      }
    }
    __syncthreads();
    #pragma unroll
    for (int p4 = 0; p4 < 4; ++p4) {
      int id = p4 * 256 + tid;
      cs[id >> 5][id & 31] = sqrtf(acc[p4]);
    }
    __syncthreads();
    if (tid >= 32) return;   // 32 lanes solve; no barriers below

    // ---- greedy assignment, reference-exact (fp64 duals) ----
    const int col = tid;
    float cc[KSL];
    #pragma unroll
    for (int r = 0; r < KSL; ++r) cc[r] = cs[r][col];  // column in VGPRs
    const double INF = __builtin_inf();
    double v = 0.0, up = 0.0;
    int pcol = 0;
    for (int i = 1; i <= KSL; ++i) {
      double u_i = 0.0;
      int used = 0;
      double cur0 = (double)sel32(cc, i - 1);   // c - u[i], u[i]=0
      for (;;) {
        double cur = cur0 - v;                  // fl(fl(c-u0)-v): ref order
        double masked = used ? INF : cur;
        double m = masked;
        m = fmin(m, dpp_mov_f64<0xB1>(m));      // quad_perm [1,0,3,2]
        m = fmin(m, dpp_mov_f64<0x4E>(m));      // quad_perm [2,3,0,1]
        m = fmin(m, dpp_mov_f64<0x141>(m));     // row_half_mirror
        m = fmin(m, dpp_mov_f64<0x140>(m));     // row_mirror
        m = fmin(m, dpp_mov_f64<0x142>(m));     // row_bcast15 -> lane31=min
        double delta = readlane_f64(m, 31);
        unsigned eq = (unsigned)__ballot(masked == delta);
        int j1c = __builtin_amdgcn_readfirstlane(__ffs(eq) - 1);
        int i0n = __builtin_amdgcn_readlane(pcol, j1c);   // p[j1]
        double u0n = readlane_f64(up, j1c);               // u[p[j1]] pre-upd
        int rown = (i0n > 0) ? (i0n - 1) : 0;
        double cur0n = (double)sel32(cc, rown) - u0n;     // next iter's c-u0
        if (used) { up += delta; v -= delta; }
        u_i += delta;
        if (i0n == 0) {                       // free column: p[j1]=i, done
          if (col == j1c) { pcol = i; up = u_i; }
          break;
        }
        if (col == j1c) used = 1;             // used[j1] = True
        cur0 = cur0n;
      }
    }
    match[b * KSL + (pcol - 1)] = col;        // ans[p[j]-1] = j-1
  } else {
    // ---- mask partial sums: partial[b][chunk][k], coalesced float4 ----
    int idx = blockIdx.x - BATCH;
    int b = idx >> 5, chunk = idx & 31;
    const int ROWS = NMASK / 32;  // 512 rows of 32 floats per chunk
    const float4* m4 = (const float4*)(masks + (size_t)b * NMASK * KSL +
                                       (size_t)chunk * ROWS * KSL);
    int q = tid & 7;
    int r = tid >> 3;
    float4 a4 = make_float4(0.f, 0.f, 0.f, 0.f);
    for (int rr = r; rr < ROWS; rr += 32) {
      float4 t = m4[rr * 8 + q];
      a4.x += t.x; a4.y += t.y; a4.z += t.z; a4.w += t.w;
    }
    __shared__ float red[256][4];
    red[tid][0] = a4.x; red[tid][1] = a4.y;
    red[tid][2] = a4.z; red[tid][3] = a4.w;
    __syncthreads();
    if (tid < KSL) {
      int qq = tid >> 2, c = tid & 3;
      float s = 0.f;
      for (int g = 0; g < 32; ++g) s += red[g * 8 + qq][c];
      partial[(size_t)b * 1024 + chunk * 32 + tid] = s;
    }
  }
}

// ---------------------------------------------------------------------------
// Finale: per-batch epilogue + deterministic last-block global reduce.
// counter is memset to 0 in-stream each call; last block (old==63) sums the
// 64 bloss values in fixed lane order -> bit-deterministic output.
// ---------------------------------------------------------------------------
__global__ __launch_bounds__(256) void finale_kernel(
    const float* __restrict__ st, const float* __restrict__ st1,
    const int* __restrict__ match, const float* __restrict__ partial,
    float* __restrict__ bloss, unsigned* __restrict__ counter,
    float* __restrict__ out) {
  int b = blockIdx.x, tid = threadIdx.x;
  __shared__ float util[KSL], ls[KSL], red[256];
  __shared__ int sh_last;
  if (tid < KSL) {
    float s = 0.f;
    for (int c = 0; c < 32; ++c) s += partial[(size_t)b * 1024 + c * 32 + tid];
    util[tid] = s;
  }
  int k = tid >> 3, l8 = tid & 7;
  int mk = match[b * KSL + k];
  const float* x = st  + ((size_t)b * KSL + k)  * DIM;
  const float* y = st1 + ((size_t)b * KSL + mk) * DIM;
  float acc = 0.f;
  for (int d = l8; d < DIM; d += 8) {
    float df = x[d] - y[d];
    acc = fmaf(df, df, acc);
  }
  red[tid] = acc;
  __syncthreads();
  if (l8 == 0) {
    float s = 0.f;
    #pragma unroll
    for (int t = 0; t < 8; ++t) s += red[tid + t];
    ls[k] = s;
  }
  __syncthreads();
  if (tid == 0) {
    float us = 0.f;
    for (int kk = 0; kk < KSL; ++kk) us += util[kk];
    float s = 0.f;
    for (int kk = 0; kk < KSL; ++kk) s += ls[kk] * (util[kk] / us);
    bloss[b] = s;
    __threadfence();                       // release bloss[b]
    unsigned old = atomicAdd(counter, 1u); // device-scope
    sh_last = (old == BATCH - 1) ? 1 : 0;
  }
  __syncthreads();
  if (sh_last && tid < 64) {
    __threadfence();                       // acquire
    float v = atomicAdd(&bloss[tid], 0.0f);  // device-scope read (x+0=x)
    #pragma unroll
    for (int off = 32; off > 0; off >>= 1) v += __shfl_down(v, off);
    if (tid == 0) out[0] = v / (float)(BATCH * KSL);
  }
}

extern "C" void kernel_launch(void* const* d_in, const int* in_sizes, int n_in,
                              void* d_out, int out_size, void* d_ws, size_t ws_size,
                              hipStream_t stream) {
  const float* slots_t  = (const float*)d_in[0];
  const float* slots_t1 = (const float*)d_in[1];
  const float* masks    = (const float*)d_in[2];

  // ws layout: match 8KB | partial 256KB | bloss 256B | counter 4B
  char* ws = (char*)d_ws;
  int*      match   = (int*)     (ws);
  float*    partial = (float*)   (ws + 8192);
  float*    bloss   = (float*)   (ws + 8192 + 262144);
  unsigned* counter = (unsigned*)(ws + 8192 + 262144 + 256);

  hipMemsetAsync(counter, 0, sizeof(unsigned), stream);
  fused_kernel<<<BATCH + BATCH * 32, 256, 0, stream>>>(slots_t, slots_t1, masks,
                                                       match, partial);
  finale_kernel<<<BATCH, 256, 0, stream>>>(slots_t, slots_t1, match, partial,
                                           bloss, counter, (float*)d_out);
}

// Round 6
// 167.541 us; speedup vs baseline: 1.0339x; 1.0339x over previous
//
#include <hip/hip_runtime.h>
#include <math.h>

#define BATCH 64
#define KSL   32
#define DIM   256
#define NMASK 16384

// DPP move of a double (both 32-bit halves), compile-time ctrl.
// bound_ctrl=false + old=src: invalid source lanes keep own value (min-safe).
template<int CTRL>
__device__ __forceinline__ double dpp_mov_f64(double x) {
  union { double d; int i[2]; } a, r;
  a.d = x;
  r.i[0] = __builtin_amdgcn_update_dpp(a.i[0], a.i[0], CTRL, 0xF, 0xF, false);
  r.i[1] = __builtin_amdgcn_update_dpp(a.i[1], a.i[1], CTRL, 0xF, 0xF, false);
  return r.d;
}

__device__ __forceinline__ double readlane_f64(double x, int lane) {
  union { double d; unsigned long long u; } a; a.d = x;
  int lo = __builtin_amdgcn_readlane((int)(a.u & 0xFFFFFFFFull), lane);
  int hi = __builtin_amdgcn_readlane((int)(a.u >> 32), lane);
  union { unsigned long long u; double d; } r;
  r.u = ((unsigned long long)(unsigned)hi << 32) | (unsigned)lo;
  return r.d;
}

// Branchless select cc[idx] (idx wave-uniform) via 5-level cndmask tree.
// All indices compile-time after unroll -> stays in registers (rule #20)
// PROVIDED the VGPR budget allows (~180); see __launch_bounds__ note below.
__device__ __forceinline__ float sel32(const float (&cc)[KSL], int idx) {
  float l0[16], l1[8], l2[4], l3[2];
  bool b4 = (idx & 16) != 0;
  #pragma unroll
  for (int r = 0; r < 16; ++r) l0[r] = b4 ? cc[r + 16] : cc[r];
  bool b3 = (idx & 8) != 0;
  #pragma unroll
  for (int r = 0; r < 8; ++r) l1[r] = b3 ? l0[r + 8] : l0[r];
  bool b2 = (idx & 4) != 0;
  #pragma unroll
  for (int r = 0; r < 4; ++r) l2[r] = b2 ? l1[r + 4] : l1[r];
  bool b1 = (idx & 2) != 0;
  #pragma unroll
  for (int r = 0; r < 2; ++r) l3[r] = b1 ? l2[r + 2] : l2[r];
  return (idx & 1) ? l3[1] : l3[0];
}

// ---------------------------------------------------------------------------
// Fused kernel:
//   blocks [0,64)        : cost matrix + reference-exact greedy assignment
//                          (fp64 duals, register-resident cost column,
//                          software-pipelined cur0 = c - u0)
//   blocks [64, 64+2048) : mask partial sums (134 MB, full-device streaming)
//
// __launch_bounds__(256, 1): min 1 wave/EU -> VGPR budget up to 512, so the
// solver's cc[32]+sel32 temporaries (~180 VGPR total) stay in registers.
// Round 4 (512thr heuristic -> 32 VGPR) and round 5 ((256,2) -> 128 VGPR)
// both spilled this array to scratch: 187/180us. Mask blocks are LDS-limited
// to 6 blocks/CU regardless, so the relaxed bound costs them nothing.
// ---------------------------------------------------------------------------
__global__ __launch_bounds__(256, 1) void fused_kernel(
    const float* __restrict__ slots_t, const float* __restrict__ slots_t1,
    const float* __restrict__ masks,
    int* __restrict__ match, float* __restrict__ partial) {
  int tid = threadIdx.x;
  if (blockIdx.x < BATCH) {
    int b = blockIdx.x;
    __shared__ float as[KSL][64];
    __shared__ float bs[KSL][65];   // pad: conflict-free vs as
    __shared__ float cs[KSL][33];   // pad: column read (r*33+col) hits
                                    // bank (r+col)%32 -> conflict-free
    const float* ab = slots_t  + (size_t)b * KSL * DIM;
    const float* bb = slots_t1 + (size_t)b * KSL * DIM;

    // ---- cost[i][j] = ||a_i - b_j|| (fp32) ----
    float acc[4] = {0.f, 0.f, 0.f, 0.f};
    for (int c = 0; c < DIM / 64; ++c) {
      __syncthreads();
      for (int e = tid; e < KSL * 64; e += 256) {
        int kk = e >> 6, dd = e & 63;
        as[kk][dd] = ab[kk * DIM + c * 64 + dd];
        bs[kk][dd] = bb[kk * DIM + c * 64 + dd];
      }
      __syncthreads();
      #pragma unroll
      for (int p4 = 0; p4 < 4; ++p4) {
        int id = p4 * 256 + tid;
        int i = id >> 5, j = id & 31;
        float s = acc[p4];
        #pragma unroll
        for (int dd = 0; dd < 64; ++dd) {
          float df = as[i][dd] - bs[j][dd];
          s = fmaf(df, df, s);
        }
        acc[p4] = s;
      }
    }
    __syncthreads();
    #pragma unroll
    for (int p4 = 0; p4 < 4; ++p4) {
      int id = p4 * 256 + tid;
      cs[id >> 5][id & 31] = sqrtf(acc[p4]);
    }
    __syncthreads();
    if (tid >= 32) return;   // 32 lanes solve; no barriers below

    // ---- greedy assignment, reference-exact (fp64 duals) ----
    const int col = tid;
    float cc[KSL];
    #pragma unroll
    for (int r = 0; r < KSL; ++r) cc[r] = cs[r][col];  // column in VGPRs
    const double INF = __builtin_inf();
    double v = 0.0, up = 0.0;
    int pcol = 0;
    for (int i = 1; i <= KSL; ++i) {
      double u_i = 0.0;
      int used = 0;
      double cur0 = (double)sel32(cc, i - 1);   // c - u[i], u[i]=0
      for (;;) {
        double cur = cur0 - v;                  // fl(fl(c-u0)-v): ref order
        double masked = used ? INF : cur;
        double m = masked;
        m = fmin(m, dpp_mov_f64<0xB1>(m));      // quad_perm [1,0,3,2]
        m = fmin(m, dpp_mov_f64<0x4E>(m));      // quad_perm [2,3,0,1]
        m = fmin(m, dpp_mov_f64<0x141>(m));     // row_half_mirror
        m = fmin(m, dpp_mov_f64<0x140>(m));     // row_mirror
        m = fmin(m, dpp_mov_f64<0x142>(m));     // row_bcast15 -> lane31=min
        double delta = readlane_f64(m, 31);
        unsigned eq = (unsigned)__ballot(masked == delta);
        int j1c = __builtin_amdgcn_readfirstlane(__ffs(eq) - 1);
        int i0n = __builtin_amdgcn_readlane(pcol, j1c);   // p[j1]
        double u0n = readlane_f64(up, j1c);               // u[p[j1]] pre-upd
        int rown = (i0n > 0) ? (i0n - 1) : 0;
        double cur0n = (double)sel32(cc, rown) - u0n;     // next iter's c-u0
        if (used) { up += delta; v -= delta; }
        u_i += delta;
        if (i0n == 0) {                       // free column: p[j1]=i, done
          if (col == j1c) { pcol = i; up = u_i; }
          break;
        }
        if (col == j1c) used = 1;             // used[j1] = True
        cur0 = cur0n;
      }
    }
    match[b * KSL + (pcol - 1)] = col;        // ans[p[j]-1] = j-1
  } else {
    // ---- mask partial sums: partial[b][chunk][k], coalesced float4 ----
    int idx = blockIdx.x - BATCH;
    int b = idx >> 5, chunk = idx & 31;
    const int ROWS = NMASK / 32;  // 512 rows of 32 floats per chunk
    const float4* m4 = (const float4*)(masks + (size_t)b * NMASK * KSL +
                                       (size_t)chunk * ROWS * KSL);
    int q = tid & 7;
    int r = tid >> 3;
    float4 a4 = make_float4(0.f, 0.f, 0.f, 0.f);
    for (int rr = r; rr < ROWS; rr += 32) {
      float4 t = m4[rr * 8 + q];
      a4.x += t.x; a4.y += t.y; a4.z += t.z; a4.w += t.w;
    }
    __shared__ float red[256][4];
    red[tid][0] = a4.x; red[tid][1] = a4.y;
    red[tid][2] = a4.z; red[tid][3] = a4.w;
    __syncthreads();
    if (tid < KSL) {
      int qq = tid >> 2, c = tid & 3;
      float s = 0.f;
      for (int g = 0; g < 32; ++g) s += red[g * 8 + qq][c];
      partial[(size_t)b * 1024 + chunk * 32 + tid] = s;
    }
  }
}

// ---------------------------------------------------------------------------
// Finale: per-batch epilogue + deterministic last-block global reduce.
// counter is memset to 0 in-stream each call; last block (old==63) sums the
// 64 bloss values in fixed lane order -> bit-deterministic output.
// ---------------------------------------------------------------------------
__global__ __launch_bounds__(256) void finale_kernel(
    const float* __restrict__ st, const float* __restrict__ st1,
    const int* __restrict__ match, const float* __restrict__ partial,
    float* __restrict__ bloss, unsigned* __restrict__ counter,
    float* __restrict__ out) {
  int b = blockIdx.x, tid = threadIdx.x;
  __shared__ float util[KSL], ls[KSL], red[256];
  __shared__ int sh_last;
  if (tid < KSL) {
    float s = 0.f;
    for (int c = 0; c < 32; ++c) s += partial[(size_t)b * 1024 + c * 32 + tid];
    util[tid] = s;
  }
  int k = tid >> 3, l8 = tid & 7;
  int mk = match[b * KSL + k];
  const float* x = st  + ((size_t)b * KSL + k)  * DIM;
  const float* y = st1 + ((size_t)b * KSL + mk) * DIM;
  float acc = 0.f;
  for (int d = l8; d < DIM; d += 8) {
    float df = x[d] - y[d];
    acc = fmaf(df, df, acc);
  }
  red[tid] = acc;
  __syncthreads();
  if (l8 == 0) {
    float s = 0.f;
    #pragma unroll
    for (int t = 0; t < 8; ++t) s += red[tid + t];
    ls[k] = s;
  }
  __syncthreads();
  if (tid == 0) {
    float us = 0.f;
    for (int kk = 0; kk < KSL; ++kk) us += util[kk];
    float s = 0.f;
    for (int kk = 0; kk < KSL; ++kk) s += ls[kk] * (util[kk] / us);
    bloss[b] = s;
    __threadfence();                       // release bloss[b]
    unsigned old = atomicAdd(counter, 1u); // device-scope
    sh_last = (old == BATCH - 1) ? 1 : 0;
  }
  __syncthreads();
  if (sh_last && tid < 64) {
    __threadfence();                       // acquire
    float v = atomicAdd(&bloss[tid], 0.0f);  // device-scope read (x+0=x)
    #pragma unroll
    for (int off = 32; off > 0; off >>= 1) v += __shfl_down(v, off);
    if (tid == 0) out[0] = v / (float)(BATCH * KSL);
  }
}

extern "C" void kernel_launch(void* const* d_in, const int* in_sizes, int n_in,
                              void* d_out, int out_size, void* d_ws, size_t ws_size,
                              hipStream_t stream) {
  const float* slots_t  = (const float*)d_in[0];
  const float* slots_t1 = (const float*)d_in[1];
  const float* masks    = (const float*)d_in[2];

  // ws layout: match 8KB | partial 256KB | bloss 256B | counter 4B
  char* ws = (char*)d_ws;
  int*      match   = (int*)     (ws);
  float*    partial = (float*)   (ws + 8192);
  float*    bloss   = (float*)   (ws + 8192 + 262144);
  unsigned* counter = (unsigned*)(ws + 8192 + 262144 + 256);

  hipMemsetAsync(counter, 0, sizeof(unsigned), stream);
  fused_kernel<<<BATCH + BATCH * 32, 256, 0, stream>>>(slots_t, slots_t1, masks,
                                                       match, partial);
  finale_kernel<<<BATCH, 256, 0, stream>>>(slots_t, slots_t1, match, partial,
                                           bloss, counter, (float*)d_out);
}

// Round 7
// 68.284 us; speedup vs baseline: 2.5367x; 2.4536x over previous
//
#include <hip/hip_runtime.h>
#include <math.h>

#define BATCH 64
#define KSL   32
#define DIM   256
#define NMASK 16384

// DPP move of a double (both 32-bit halves), compile-time ctrl.
// bound_ctrl=false + old=src: invalid source lanes keep own value (min-safe).
template<int CTRL>
__device__ __forceinline__ double dpp_mov_f64(double x) {
  union { double d; int i[2]; } a, r;
  a.d = x;
  r.i[0] = __builtin_amdgcn_update_dpp(a.i[0], a.i[0], CTRL, 0xF, 0xF, false);
  r.i[1] = __builtin_amdgcn_update_dpp(a.i[1], a.i[1], CTRL, 0xF, 0xF, false);
  return r.d;
}

__device__ __forceinline__ double readlane_f64(double x, int lane) {
  union { double d; unsigned long long u; } a; a.d = x;
  int lo = __builtin_amdgcn_readlane((int)(a.u & 0xFFFFFFFFull), lane);
  int hi = __builtin_amdgcn_readlane((int)(a.u >> 32), lane);
  union { unsigned long long u; double d; } r;
  r.u = ((unsigned long long)(unsigned)hi << 32) | (unsigned)lo;
  return r.d;
}

// ---------------------------------------------------------------------------
// Fused kernel (round-3 proven structure; solver ds_read software-pipelined):
//   blocks [0,64)        : cost matrix + reference-exact greedy assignment
//                          (fp64 duals; cost row read from LDS, prefetched
//                          one iteration ahead so ds_read latency overlaps
//                          the dual-update + branch bookkeeping)
//   blocks [64, 64+2048) : mask partial sums (134 MB, full-device streaming)
// NOTE: register-column + cndmask-select solver (rounds 4-6) was 3x SLOWER
// (scratch/issue-bound) at every launch-bounds setting. Do not reintroduce.
// ---------------------------------------------------------------------------
__global__ __launch_bounds__(256) void fused_kernel(
    const float* __restrict__ slots_t, const float* __restrict__ slots_t1,
    const float* __restrict__ masks,
    int* __restrict__ match, float* __restrict__ partial) {
  int tid = threadIdx.x;
  if (blockIdx.x < BATCH) {
    int b = blockIdx.x;
    __shared__ float as[KSL][64];
    __shared__ float bs[KSL][65];   // pad: conflict-free
    __shared__ float cs[KSL][KSL];  // row-read by solver: consecutive -> ok
    const float* ab = slots_t  + (size_t)b * KSL * DIM;
    const float* bb = slots_t1 + (size_t)b * KSL * DIM;

    // ---- cost[i][j] = ||a_i - b_j|| (fp32) ----
    float acc[4] = {0.f, 0.f, 0.f, 0.f};
    for (int c = 0; c < DIM / 64; ++c) {
      __syncthreads();
      for (int e = tid; e < KSL * 64; e += 256) {
        int kk = e >> 6, dd = e & 63;
        as[kk][dd] = ab[kk * DIM + c * 64 + dd];
        bs[kk][dd] = bb[kk * DIM + c * 64 + dd];
      }
      __syncthreads();
      #pragma unroll
      for (int p4 = 0; p4 < 4; ++p4) {
        int id = p4 * 256 + tid;
        int i = id >> 5, j = id & 31;
        float s = acc[p4];
        #pragma unroll
        for (int dd = 0; dd < 64; ++dd) {
          float df = as[i][dd] - bs[j][dd];
          s = fmaf(df, df, s);
        }
        acc[p4] = s;
      }
    }
    __syncthreads();
    #pragma unroll
    for (int p4 = 0; p4 < 4; ++p4) {
      int id = p4 * 256 + tid;
      cs[id >> 5][id & 31] = sqrtf(acc[p4]);
    }
    __syncthreads();
    if (tid >= 32) return;   // 32 lanes solve; no barriers below

    // ---- greedy assignment, reference-exact (fp64 duals) ----
    // lane col holds: v[col+1], p[col+1] (pcol), u[p[col+1]] (up)
    const int col = tid;
    const double INF = __builtin_inf();
    double v = 0.0, up = 0.0;
    int pcol = 0;
    // pipelined: (cF, u0c) = cost-row value and matching u[i0] for the
    // UPCOMING iteration; ds_read issued one iteration early.
    float  cF  = cs[0][col];   // row 0 for i=1 (u[1] = 0)
    double u0c = 0.0;
    for (int i = 1; i <= KSL; ++i) {
      double u_i = 0.0;
      int used = 0;
      for (;;) {
        double cur = (double)cF - u0c - v;   // fl(fl(c-u0)-v): ref order
        double masked = used ? INF : cur;
        double m = masked;
        m = fmin(m, dpp_mov_f64<0xB1>(m));   // quad_perm [1,0,3,2]
        m = fmin(m, dpp_mov_f64<0x4E>(m));   // quad_perm [2,3,0,1]
        m = fmin(m, dpp_mov_f64<0x141>(m));  // row_half_mirror
        m = fmin(m, dpp_mov_f64<0x140>(m));  // row_mirror
        m = fmin(m, dpp_mov_f64<0x142>(m));  // row_bcast15 -> lane31 = min32
        double delta = readlane_f64(m, 31);
        unsigned eq = (unsigned)__ballot(masked == delta);
        int j1c = __builtin_amdgcn_readfirstlane(__ffs(eq) - 1);
        int i0n = __builtin_amdgcn_readlane(pcol, j1c);   // p[j1]
        double u0n = readlane_f64(up, j1c);               // u[p[j1]] (j1 was
                                                          // unused -> pre-upd
                                                          // value is correct)
        // prefetch next row: continue -> row i0n-1; break -> row i (outer
        // i+1, 0-based). i&31 keeps the dummy last read in-bounds.
        int nextrow = (i0n > 0) ? (i0n - 1) : (i & (KSL - 1));
        cF  = cs[nextrow][col];              // ds_read: consumed next loop top
        u0c = (i0n > 0) ? u0n : 0.0;
        // dual updates: u[p[j]] += delta, v[j] -= delta for used j; u[i] too
        if (used) { up += delta; v -= delta; }
        u_i += delta;
        if (i0n == 0) {                      // free column: p[j1]=i, done
          if (col == j1c) { pcol = i; up = u_i; }
          break;
        }
        if (col == j1c) used = 1;            // used[j1] = True
      }
    }
    match[b * KSL + (pcol - 1)] = col;       // ans[p[j]-1] = j-1
  } else {
    // ---- mask partial sums: partial[b][chunk][k], coalesced float4 ----
    int idx = blockIdx.x - BATCH;
    int b = idx >> 5, chunk = idx & 31;
    const int ROWS = NMASK / 32;  // 512 rows of 32 floats per chunk
    const float4* m4 = (const float4*)(masks + (size_t)b * NMASK * KSL +
                                       (size_t)chunk * ROWS * KSL);
    int q = tid & 7;
    int r = tid >> 3;
    float4 a4 = make_float4(0.f, 0.f, 0.f, 0.f);
    for (int rr = r; rr < ROWS; rr += 32) {
      float4 t = m4[rr * 8 + q];
      a4.x += t.x; a4.y += t.y; a4.z += t.z; a4.w += t.w;
    }
    __shared__ float red[256][4];
    red[tid][0] = a4.x; red[tid][1] = a4.y;
    red[tid][2] = a4.z; red[tid][3] = a4.w;
    __syncthreads();
    if (tid < KSL) {
      int qq = tid >> 2, c = tid & 3;
      float s = 0.f;
      for (int g = 0; g < 32; ++g) s += red[g * 8 + qq][c];
      partial[(size_t)b * 1024 + chunk * 32 + tid] = s;
    }
  }
}

// ---------------------------------------------------------------------------
// Finale: per-batch epilogue + deterministic last-block global reduce.
// counter memset to 0 in-stream each call; last block (old==63) sums the
// 64 bloss values in fixed lane order -> bit-deterministic output.
// ---------------------------------------------------------------------------
__global__ __launch_bounds__(256) void finale_kernel(
    const float* __restrict__ st, const float* __restrict__ st1,
    const int* __restrict__ match, const float* __restrict__ partial,
    float* __restrict__ bloss, unsigned* __restrict__ counter,
    float* __restrict__ out) {
  int b = blockIdx.x, tid = threadIdx.x;
  __shared__ float util[KSL], ls[KSL], red[256];
  __shared__ int sh_last;
  if (tid < KSL) {
    float s = 0.f;
    for (int c = 0; c < 32; ++c) s += partial[(size_t)b * 1024 + c * 32 + tid];
    util[tid] = s;
  }
  int k = tid >> 3, l8 = tid & 7;
  int mk = match[b * KSL + k];
  const float* x = st  + ((size_t)b * KSL + k)  * DIM;
  const float* y = st1 + ((size_t)b * KSL + mk) * DIM;
  float acc = 0.f;
  for (int d = l8; d < DIM; d += 8) {
    float df = x[d] - y[d];
    acc = fmaf(df, df, acc);
  }
  red[tid] = acc;
  __syncthreads();
  if (l8 == 0) {
    float s = 0.f;
    #pragma unroll
    for (int t = 0; t < 8; ++t) s += red[tid + t];
    ls[k] = s;
  }
  __syncthreads();
  if (tid == 0) {
    float us = 0.f;
    for (int kk = 0; kk < KSL; ++kk) us += util[kk];
    float s = 0.f;
    for (int kk = 0; kk < KSL; ++kk) s += ls[kk] * (util[kk] / us);
    bloss[b] = s;
    __threadfence();                       // release bloss[b]
    unsigned old = atomicAdd(counter, 1u); // device-scope
    sh_last = (old == BATCH - 1) ? 1 : 0;
  }
  __syncthreads();
  if (sh_last && tid < 64) {
    __threadfence();                       // acquire
    float v = atomicAdd(&bloss[tid], 0.0f);  // device-scope read (x+0=x)
    #pragma unroll
    for (int off = 32; off > 0; off >>= 1) v += __shfl_down(v, off);
    if (tid == 0) out[0] = v / (float)(BATCH * KSL);
  }
}

extern "C" void kernel_launch(void* const* d_in, const int* in_sizes, int n_in,
                              void* d_out, int out_size, void* d_ws, size_t ws_size,
                              hipStream_t stream) {
  const float* slots_t  = (const float*)d_in[0];
  const float* slots_t1 = (const float*)d_in[1];
  const float* masks    = (const float*)d_in[2];

  // ws layout: match 8KB | partial 256KB | bloss 256B | counter 4B
  char* ws = (char*)d_ws;
  int*      match   = (int*)     (ws);
  float*    partial = (float*)   (ws + 8192);
  float*    bloss   = (float*)   (ws + 8192 + 262144);
  unsigned* counter = (unsigned*)(ws + 8192 + 262144 + 256);

  hipMemsetAsync(counter, 0, sizeof(unsigned), stream);
  fused_kernel<<<BATCH + BATCH * 32, 256, 0, stream>>>(slots_t, slots_t1, masks,
                                                       match, partial);
  finale_kernel<<<BATCH, 256, 0, stream>>>(slots_t, slots_t1, match, partial,
                                           bloss, counter, (float*)d_out);
}